// Round 2
// baseline (2456.256 us; speedup 1.0000x reference)
//
#include <hip/hip_runtime.h>

#define TT 512
#define NB 1024
#define SS 64
#define HH 128
#define NA 10

typedef short bf16x8 __attribute__((ext_vector_type(8)));
typedef float f32x4 __attribute__((ext_vector_type(4)));
typedef unsigned short u16;
typedef unsigned int u32;

__device__ __forceinline__ u16 f2bf(float f){
  union { float f; u32 u; } v; v.f = f;
  return (u16)((v.u + 0x7FFFu + ((v.u >> 16) & 1u)) >> 16);
}

__device__ __forceinline__ float sigm(float v){
  return __builtin_amdgcn_rcpf(1.f + __builtin_amdgcn_exp2f(-1.442695040888963f * v));
}
__device__ __forceinline__ float tanh_(float v){
  return 1.f - 2.f * __builtin_amdgcn_rcpf(1.f + __builtin_amdgcn_exp2f(2.885390081777927f * v));
}

// Pack W_hh2 into bf16 MFMA B-fragment order in d_ws (the only per-step L2-streamed
// weight). Wave w, ktile kt, gate g, lane L reads 16B at w*8192 + (kt*4+g)*512 + L*8;
// element e is col = 128g + 16w + (L&15), k = kt*32 + (L>>4)*8 + e.
__global__ void pack_whh2(const float* __restrict__ Whh2, u16* __restrict__ ws){
  int i = blockIdx.x * 256 + threadIdx.x;   // 65536 total
  int e = i & 7, L = (i >> 3) & 63, fg = i >> 9;
  int g = fg & 3, wk = fg >> 2, kt = wk & 3, w = wk >> 2;
  int col = 128*g + 16*w + (L & 15);
  int k = kt*32 + (L >> 4)*8 + e;
  ws[i] = f2bf(Whh2[col*HH + k]);
}

// 64 blocks x 512 threads (8 waves). Block owns batch rows [16b,16b+16) for all T.
// Wave w owns h-feature slice [16w,16w+16) and its 4 gate tiles (i,f,g,o).
// h1s/h2s/xs in A-fragment granule order: elem (row,j) -> u16 idx ((j>>3)*16+row)*8+(j&7)
// so lane L's A-frag for ktile kt is a linear ds_read_b128 at u16 idx kt*512 + L*8.
//
// 3-barrier step schedule (trans/MFMA overlap within regions):
//  R1: stage x(t)                               | alpha
//  R2: proj h2(t-1) [w0]; acc1 += x@Wih1 (LDS)  | beta
//  R3: L1 act -> h1s(t)  ||  acc2 = b2 + h2(t-1)@Whh2 (L2 stream)  | gamma
//  R4: acc2 += h1(t)@Wih2; L2 act -> h2s(t)  ||  acc1' = b1 + h1(t)@Whh1
__global__ __launch_bounds__(512, 2)
void lstm_fused(const float* __restrict__ x,
                const float* __restrict__ Whh1f,
                const float* __restrict__ bih1, const float* __restrict__ bhh1,
                const float* __restrict__ Wih1f,
                const float* __restrict__ Wih2f,
                const float* __restrict__ bih2, const float* __restrict__ bhh2,
                const float* __restrict__ Woutf, const float* __restrict__ boutf,
                const u16* __restrict__ wsp,
                float* __restrict__ out)
{
  __shared__ __align__(16) u16 h1s[2048];
  __shared__ __align__(16) u16 h2s[2048];
  __shared__ __align__(16) u16 xs[1024];
  __shared__ __align__(16) u16 wos[2048];
  __shared__ __align__(16) u16 wih1s[32768];   // W_ih1 B-fragments, resident

  const int tid = threadIdx.x;
  const int w   = tid >> 6;
  const int L   = tid & 63;
  const int Llo = L & 15;
  const int Lhi = L >> 4;
  const int batch0 = blockIdx.x * 16;

  // ---- one-time: register-resident W_hh1, W_ih2 (bf16 B-fragments) ----
  bf16x8 Whh1r[4][4], Wih2r[4][4];
#pragma unroll
  for (int kt = 0; kt < 4; ++kt)
#pragma unroll
    for (int g = 0; g < 4; ++g){
      int col = 128*g + 16*w + Llo;
      const float* p1 = Whh1f + col*HH + kt*32 + Lhi*8;
      const float* p2 = Wih2f + col*HH + kt*32 + Lhi*8;
      bf16x8 v1, v2;
#pragma unroll
      for (int e = 0; e < 8; ++e){ v1[e] = (short)f2bf(p1[e]); v2[e] = (short)f2bf(p2[e]); }
      Whh1r[kt][g] = v1; Wih2r[kt][g] = v2;
    }

  float bias1[4], bias2[4];
#pragma unroll
  for (int g = 0; g < 4; ++g){
    int col = 128*g + 16*w + Llo;
    bias1[g] = bih1[col] + bhh1[col];
    bias2[g] = bih2[col] + bhh2[col];
  }
  const float boutr = (Llo < NA) ? boutf[Llo] : 0.f;

  // W_out fragments -> LDS (K=128 x N=16, cols >= NA zeroed)
  if (tid < 256){
    int kt = tid >> 6, l = tid & 63, llo = l & 15, lhi = (l >> 4) & 3;
    bf16x8 v;
#pragma unroll
    for (int e = 0; e < 8; ++e) v[e] = 0;
    if (llo < NA){
      const float* p = Woutf + llo*HH + kt*32 + lhi*8;
#pragma unroll
      for (int e = 0; e < 8; ++e) v[e] = (short)f2bf(p[e]);
    }
    *reinterpret_cast<bf16x8*>(&wos[kt*512 + l*8]) = v;
  }

  // W_ih1 fragments -> LDS: u16 idx = w*4096 + (kt*4+g)*512 + L*8 + e
#pragma unroll
  for (int it = 0; it < 64; ++it){
    int i = it*512 + tid;
    int e = i & 7, l = (i >> 3) & 63, fg = i >> 9;
    int g = fg & 3, kt = (fg >> 2) & 1, ww = fg >> 3;
    int col = 128*g + 16*ww + (l & 15);
    int k = kt*32 + (l >> 4)*8 + e;
    wih1s[i] = f2bf(Wih1f[col*SS + k]);
  }

  // zero h1/h2
  *reinterpret_cast<uint2*>(&h1s[tid*4]) = make_uint2(0u, 0u);
  *reinterpret_cast<uint2*>(&h2s[tid*4]) = make_uint2(0u, 0u);

  f32x4 c1 = {0.f,0.f,0.f,0.f}, c2 = {0.f,0.f,0.f,0.f};
  f32x4 acc1[4];
#pragma unroll
  for (int g = 0; g < 4; ++g) acc1[g] = (f32x4){bias1[g], bias1[g], bias1[g], bias1[g]};

  __syncthreads();

  const int afrag = L*8;                                           // + kt*512
  const int hwIdx = (2*w + (Llo >> 3))*128 + Lhi*32 + (Llo & 7);   // + r*8
  const u16* ws_whh2 = wsp + w*8192;
  const int wih1b = w*4096;

  const int xrow = tid >> 5;
  const int xj   = (tid & 31)*2;
  const int xsIdx = ((xj >> 3)*16 + xrow)*8 + (xj & 7);

  for (int t = 0; t < TT; ++t){
    // ---- R1: stage x(t) into LDS (bf16, fragment order) ----
    {
      float2 xv = *reinterpret_cast<const float2*>(x + ((size_t)t*NB + batch0 + xrow)*SS + xj);
      u32 packed = (u32)f2bf(xv.x) | ((u32)f2bf(xv.y) << 16);
      *reinterpret_cast<u32*>(&xs[xsIdx]) = packed;
    }
    __syncthreads();   // alpha: x staged; h2s(t-1) final

    // ---- R2: projection of h2(t-1) on wave 0; acc1 += x@Wih1^T ----
    if (w == 0 && t > 0){
      f32x4 pacc = {boutr, boutr, boutr, boutr};
#pragma unroll
      for (int kt = 0; kt < 4; ++kt){
        bf16x8 ha = *reinterpret_cast<const bf16x8*>(&h2s[kt*512 + afrag]);
        bf16x8 wb = *reinterpret_cast<const bf16x8*>(&wos[kt*512 + afrag]);
        pacc = __builtin_amdgcn_mfma_f32_16x16x32_bf16(ha, wb, pacc, 0, 0, 0);
      }
      if (Llo < NA){
        size_t o = ((size_t)(t-1)*NB + batch0 + Lhi*4)*NA + Llo;
#pragma unroll
        for (int r = 0; r < 4; ++r) out[o + (size_t)r*NA] = pacc[r];
      }
    }
    {
      bf16x8 xf0 = *reinterpret_cast<const bf16x8*>(&xs[afrag]);
      bf16x8 xf1 = *reinterpret_cast<const bf16x8*>(&xs[512 + afrag]);
#pragma unroll
      for (int g = 0; g < 4; ++g){
        bf16x8 w0 = *reinterpret_cast<const bf16x8*>(&wih1s[wih1b + g*512 + afrag]);
        bf16x8 w1 = *reinterpret_cast<const bf16x8*>(&wih1s[wih1b + (4+g)*512 + afrag]);
        acc1[g] = __builtin_amdgcn_mfma_f32_16x16x32_bf16(xf0, w0, acc1[g], 0, 0, 0);
        acc1[g] = __builtin_amdgcn_mfma_f32_16x16x32_bf16(xf1, w1, acc1[g], 0, 0, 0);
      }
    }
    __syncthreads();   // beta: xs reads done; h2s proj-read done

    // ---- R3: L1 activations -> h1s(t)  ||  acc2 = b2 + h2(t-1)@Whh2^T (L2 stream) ----
    f32x4 acc2[4];
    {
      // issue kt=0,1 weight + h2 fragment loads
      bf16x8 h2f0 = *reinterpret_cast<const bf16x8*>(&h2s[afrag]);
      bf16x8 h2f1 = *reinterpret_cast<const bf16x8*>(&h2s[512 + afrag]);
      bf16x8 wb00 = *reinterpret_cast<const bf16x8*>(ws_whh2 + 0*512 + afrag);
      bf16x8 wb01 = *reinterpret_cast<const bf16x8*>(ws_whh2 + 1*512 + afrag);
      bf16x8 wb02 = *reinterpret_cast<const bf16x8*>(ws_whh2 + 2*512 + afrag);
      bf16x8 wb03 = *reinterpret_cast<const bf16x8*>(ws_whh2 + 3*512 + afrag);
      bf16x8 wb10 = *reinterpret_cast<const bf16x8*>(ws_whh2 + 4*512 + afrag);
      bf16x8 wb11 = *reinterpret_cast<const bf16x8*>(ws_whh2 + 5*512 + afrag);
      bf16x8 wb12 = *reinterpret_cast<const bf16x8*>(ws_whh2 + 6*512 + afrag);
      bf16x8 wb13 = *reinterpret_cast<const bf16x8*>(ws_whh2 + 7*512 + afrag);

      // L1 activations r=0,1 (trans pipe; hides L2 latency)
#pragma unroll
      for (int r = 0; r < 2; ++r){
        float iv = sigm(acc1[0][r]);
        float fv = sigm(acc1[1][r]);
        float gv = tanh_(acc1[2][r]);
        float ov = sigm(acc1[3][r]);
        float cn = fv*c1[r] + iv*gv;
        c1[r] = cn;
        h1s[hwIdx + r*8] = f2bf(ov * tanh_(cn));
      }

#pragma unroll
      for (int g = 0; g < 4; ++g) acc2[g] = (f32x4){bias2[g], bias2[g], bias2[g], bias2[g]};
      acc2[0] = __builtin_amdgcn_mfma_f32_16x16x32_bf16(h2f0, wb00, acc2[0], 0, 0, 0);
      acc2[1] = __builtin_amdgcn_mfma_f32_16x16x32_bf16(h2f0, wb01, acc2[1], 0, 0, 0);
      acc2[2] = __builtin_amdgcn_mfma_f32_16x16x32_bf16(h2f0, wb02, acc2[2], 0, 0, 0);
      acc2[3] = __builtin_amdgcn_mfma_f32_16x16x32_bf16(h2f0, wb03, acc2[3], 0, 0, 0);
      acc2[0] = __builtin_amdgcn_mfma_f32_16x16x32_bf16(h2f1, wb10, acc2[0], 0, 0, 0);
      acc2[1] = __builtin_amdgcn_mfma_f32_16x16x32_bf16(h2f1, wb11, acc2[1], 0, 0, 0);
      acc2[2] = __builtin_amdgcn_mfma_f32_16x16x32_bf16(h2f1, wb12, acc2[2], 0, 0, 0);
      acc2[3] = __builtin_amdgcn_mfma_f32_16x16x32_bf16(h2f1, wb13, acc2[3], 0, 0, 0);

      // issue kt=2,3 loads
      bf16x8 h2f2 = *reinterpret_cast<const bf16x8*>(&h2s[2*512 + afrag]);
      bf16x8 h2f3 = *reinterpret_cast<const bf16x8*>(&h2s[3*512 + afrag]);
      bf16x8 wb20 = *reinterpret_cast<const bf16x8*>(ws_whh2 + 8*512 + afrag);
      bf16x8 wb21 = *reinterpret_cast<const bf16x8*>(ws_whh2 + 9*512 + afrag);
      bf16x8 wb22 = *reinterpret_cast<const bf16x8*>(ws_whh2 + 10*512 + afrag);
      bf16x8 wb23 = *reinterpret_cast<const bf16x8*>(ws_whh2 + 11*512 + afrag);
      bf16x8 wb30 = *reinterpret_cast<const bf16x8*>(ws_whh2 + 12*512 + afrag);
      bf16x8 wb31 = *reinterpret_cast<const bf16x8*>(ws_whh2 + 13*512 + afrag);
      bf16x8 wb32 = *reinterpret_cast<const bf16x8*>(ws_whh2 + 14*512 + afrag);
      bf16x8 wb33 = *reinterpret_cast<const bf16x8*>(ws_whh2 + 15*512 + afrag);

      // L1 activations r=2,3
#pragma unroll
      for (int r = 2; r < 4; ++r){
        float iv = sigm(acc1[0][r]);
        float fv = sigm(acc1[1][r]);
        float gv = tanh_(acc1[2][r]);
        float ov = sigm(acc1[3][r]);
        float cn = fv*c1[r] + iv*gv;
        c1[r] = cn;
        h1s[hwIdx + r*8] = f2bf(ov * tanh_(cn));
      }

      acc2[0] = __builtin_amdgcn_mfma_f32_16x16x32_bf16(h2f2, wb20, acc2[0], 0, 0, 0);
      acc2[1] = __builtin_amdgcn_mfma_f32_16x16x32_bf16(h2f2, wb21, acc2[1], 0, 0, 0);
      acc2[2] = __builtin_amdgcn_mfma_f32_16x16x32_bf16(h2f2, wb22, acc2[2], 0, 0, 0);
      acc2[3] = __builtin_amdgcn_mfma_f32_16x16x32_bf16(h2f2, wb23, acc2[3], 0, 0, 0);
      acc2[0] = __builtin_amdgcn_mfma_f32_16x16x32_bf16(h2f3, wb30, acc2[0], 0, 0, 0);
      acc2[1] = __builtin_amdgcn_mfma_f32_16x16x32_bf16(h2f3, wb31, acc2[1], 0, 0, 0);
      acc2[2] = __builtin_amdgcn_mfma_f32_16x16x32_bf16(h2f3, wb32, acc2[2], 0, 0, 0);
      acc2[3] = __builtin_amdgcn_mfma_f32_16x16x32_bf16(h2f3, wb33, acc2[3], 0, 0, 0);
    }
    __syncthreads();   // gamma: h1s(t) complete; h2s(t-1) reads retired

    // ---- R4: acc2 += h1(t)@Wih2^T; L2 act -> h2s(t)  ||  acc1' = b1 + h1(t)@Whh1^T ----
    {
      bf16x8 hf0 = *reinterpret_cast<const bf16x8*>(&h1s[afrag]);
      bf16x8 hf1 = *reinterpret_cast<const bf16x8*>(&h1s[512 + afrag]);
      bf16x8 hf2 = *reinterpret_cast<const bf16x8*>(&h1s[2*512 + afrag]);
      bf16x8 hf3 = *reinterpret_cast<const bf16x8*>(&h1s[3*512 + afrag]);

#pragma unroll
      for (int g = 0; g < 4; ++g){
        acc2[g] = __builtin_amdgcn_mfma_f32_16x16x32_bf16(hf0, Wih2r[0][g], acc2[g], 0, 0, 0);
        acc2[g] = __builtin_amdgcn_mfma_f32_16x16x32_bf16(hf1, Wih2r[1][g], acc2[g], 0, 0, 0);
        acc2[g] = __builtin_amdgcn_mfma_f32_16x16x32_bf16(hf2, Wih2r[2][g], acc2[g], 0, 0, 0);
        acc2[g] = __builtin_amdgcn_mfma_f32_16x16x32_bf16(hf3, Wih2r[3][g], acc2[g], 0, 0, 0);
      }

      // next-step L1 h-side (independent of the activation below -> overlaps trans)
#pragma unroll
      for (int g = 0; g < 4; ++g){
        f32x4 a = (f32x4){bias1[g], bias1[g], bias1[g], bias1[g]};
        a = __builtin_amdgcn_mfma_f32_16x16x32_bf16(hf0, Whh1r[0][g], a, 0, 0, 0);
        a = __builtin_amdgcn_mfma_f32_16x16x32_bf16(hf1, Whh1r[1][g], a, 0, 0, 0);
        a = __builtin_amdgcn_mfma_f32_16x16x32_bf16(hf2, Whh1r[2][g], a, 0, 0, 0);
        a = __builtin_amdgcn_mfma_f32_16x16x32_bf16(hf3, Whh1r[3][g], a, 0, 0, 0);
        acc1[g] = a;
      }

      // L2 activations -> h2s(t)
#pragma unroll
      for (int r = 0; r < 4; ++r){
        float iv = sigm(acc2[0][r]);
        float fv = sigm(acc2[1][r]);
        float gv = tanh_(acc2[2][r]);
        float ov = sigm(acc2[3][r]);
        float cn = fv*c2[r] + iv*gv;
        c2[r] = cn;
        h2s[hwIdx + r*8] = f2bf(ov * tanh_(cn));
      }
    }
    // next iteration's alpha orders h2s writes before proj/R3 reads
  }

  __syncthreads();
  // final projection for t = TT-1
  if (w == 0){
    f32x4 pacc = {boutr, boutr, boutr, boutr};
#pragma unroll
    for (int kt = 0; kt < 4; ++kt){
      bf16x8 ha = *reinterpret_cast<const bf16x8*>(&h2s[kt*512 + afrag]);
      bf16x8 wb = *reinterpret_cast<const bf16x8*>(&wos[kt*512 + afrag]);
      pacc = __builtin_amdgcn_mfma_f32_16x16x32_bf16(ha, wb, pacc, 0, 0, 0);
    }
    if (Llo < NA){
      size_t o = ((size_t)(TT-1)*NB + batch0 + Lhi*4)*NA + Llo;
#pragma unroll
      for (int r = 0; r < 4; ++r) out[o + (size_t)r*NA] = pacc[r];
    }
  }
}

extern "C" void kernel_launch(void* const* d_in, const int* in_sizes, int n_in,
                              void* d_out, int out_size, void* d_ws, size_t ws_size,
                              hipStream_t stream){
  (void)in_sizes; (void)n_in; (void)out_size; (void)ws_size;
  const float* xp   = (const float*)d_in[0];
  const float* wih1 = (const float*)d_in[1];
  const float* whh1 = (const float*)d_in[2];
  const float* bih1 = (const float*)d_in[3];
  const float* bhh1 = (const float*)d_in[4];
  const float* wih2 = (const float*)d_in[5];
  const float* whh2 = (const float*)d_in[6];
  const float* bih2 = (const float*)d_in[7];
  const float* bhh2 = (const float*)d_in[8];
  const float* wout = (const float*)d_in[9];
  const float* bout = (const float*)d_in[10];
  u16*   wsp  = (u16*)d_ws;
  float* outp = (float*)d_out;

  hipLaunchKernelGGL(pack_whh2, dim3(256), dim3(256), 0, stream, whh2, wsp);
  hipLaunchKernelGGL(lstm_fused, dim3(64), dim3(512), 0, stream,
                     xp, whh1, bih1, bhh1, wih1, wih2, bih2, bhh2, wout, bout, wsp, outp);
}